// Round 1
// baseline (136.572 us; speedup 1.0000x reference)
//
#include <hip/hip_runtime.h>
#include <hip/hip_bf16.h>
#include <stdint.h>

#define BATCH 8192
#define DIM   512
#define BM    256
#define BK    64
#define NT    (BATCH / BM)            // 32 tiles per dim
#define NPAIR (NT * (NT + 1) / 2)     // 528 upper-triangle tile pairs

// Fb = F_norm * sqrt(log2(e)/T) so acc = Fb·Fbᵀ is already log2-domain logits.
#define FEAT_SCALE 4.5398164f         // sqrt(1.4426950409/0.07)
#define LN2        0.69314718055994531f

typedef __attribute__((ext_vector_type(8))) short short8;
typedef __attribute__((ext_vector_type(4))) float f32x4;

__device__ __forceinline__ void gld_lds16(const void* g, void* l) {
  __builtin_amdgcn_global_load_lds(
      (__attribute__((address_space(1))) void*)(uintptr_t)g,
      (__attribute__((address_space(3))) void*)(uintptr_t)l,
      16, 0, 0);
}

// ---------------------------------------------------------------------------
// Kernel 1: row-normalize fp32 -> bf16 * FEAT_SCALE. One wave per row.
// ---------------------------------------------------------------------------
__global__ __launch_bounds__(256) void normalize_bf16(
    const float* __restrict__ x, __hip_bfloat16* __restrict__ o,
    float* __restrict__ rowsum) {
  const int wv = threadIdx.x >> 6, lane = threadIdx.x & 63;
  const int row = blockIdx.x * 4 + wv;
  if (lane == 0) rowsum[row] = 0.0f;
  const float4* xr = (const float4*)(x + (size_t)row * DIM);
  const float4 v0 = xr[lane];
  const float4 v1 = xr[lane + 64];
  float ss = v0.x * v0.x + v0.y * v0.y + v0.z * v0.z + v0.w * v0.w +
             v1.x * v1.x + v1.y * v1.y + v1.z * v1.z + v1.w * v1.w;
#pragma unroll
  for (int m = 32; m > 0; m >>= 1) ss += __shfl_xor(ss, m, 64);
  const float inv = FEAT_SCALE / fmaxf(sqrtf(ss), 1e-12f);
  ushort4 p0, p1;
  p0.x = __bfloat16_as_ushort(__float2bfloat16(v0.x * inv));
  p0.y = __bfloat16_as_ushort(__float2bfloat16(v0.y * inv));
  p0.z = __bfloat16_as_ushort(__float2bfloat16(v0.z * inv));
  p0.w = __bfloat16_as_ushort(__float2bfloat16(v0.w * inv));
  p1.x = __bfloat16_as_ushort(__float2bfloat16(v1.x * inv));
  p1.y = __bfloat16_as_ushort(__float2bfloat16(v1.y * inv));
  p1.z = __bfloat16_as_ushort(__float2bfloat16(v1.z * inv));
  p1.w = __bfloat16_as_ushort(__float2bfloat16(v1.w * inv));
  ushort4* orow = (ushort4*)(o + (size_t)row * DIM);
  orow[lane]      = p0;
  orow[lane + 64] = p1;
}

// ---------------------------------------------------------------------------
// Kernel 2: 256x256 bf16 tiles, 8 waves (2Mx4N), 8-phase pipelined schedule.
// LDS: 2 dbuf x {A,B} x {kk0,kk1} planes of [256 rows][32 k] (16 KB each) =
// 128 KiB + 1 KB colAcc. Raw s_barrier (NO vmcnt drain); counted vmcnt(4)
// only at phases 3/7; setprio around each 16-MFMA cluster.
// Staging is pre-swizzled at the global source (slot^ = row&3), reads apply
// the same involution -> bank-balanced ds_read_b128 (both-sides-or-neither).
// Last iteration's prefetches wrap to tiles 0/1 (harmless) so vmcnt counts
// stay uniform; one vmcnt(0) drain before the epilogue reuses staging LDS.
// ---------------------------------------------------------------------------
__global__ __launch_bounds__(512, 2) void sim_lse_kernel(
    const __hip_bfloat16* __restrict__ F, float* __restrict__ rowsum,
    float* __restrict__ possim) {
  extern __shared__ char smem[];
  float* colAcc = (float*)(smem + 131072);

  const int t = blockIdx.x;
  int by = (int)((65.0f - sqrtf(65.0f * 65.0f - 8.0f * (float)t)) * 0.5f);
  if (by > NT - 1) by = NT - 1;
  if (by < 0) by = 0;
  while ((by + 1) * (65 - (by + 1)) / 2 <= t) ++by;
  while (by * (65 - by) / 2 > t) --by;
  const int bx = by + (t - by * (65 - by) / 2);
  const bool diagTile = (bx == by);
  const bool hasPos = (bx == by + NT / 2);

  const int rowBase = by * BM;
  const int colBase = bx * BM;

  const int tid  = threadIdx.x;
  const int lane = tid & 63;
  const int wv   = tid >> 6;
  const int q    = lane >> 4;
  const int l15  = lane & 15;
  const int waveM = wv >> 2;   // 0..1 -> 128-row half
  const int waveN = wv & 3;    // 0..3 -> 64-col quarter

  // staging sources (pre-swizzled 16B segment: s ^ (row&3))
  const int r0 = tid >> 2, s0 = tid & 3;
  const int r1 = (tid + 512) >> 2;                 // (tid+512)&3 == s0
  const __hip_bfloat16* gA0 = F + (size_t)(rowBase + r0) * DIM + (s0 ^ (r0 & 3)) * 8;
  const __hip_bfloat16* gA1 = F + (size_t)(rowBase + r1) * DIM + (s0 ^ (r1 & 3)) * 8;
  const __hip_bfloat16* gB0 = F + (size_t)(colBase + r0) * DIM + (s0 ^ (r0 & 3)) * 8;
  const __hip_bfloat16* gB1 = F + (size_t)(colBase + r1) * DIM + (s0 ^ (r1 & 3)) * 8;
  char* ldsW0 = smem + wv * 1024;   // HW scatters +lane*16
  char* ldsW1 = ldsW0 + 8192;

  // ds_read offsets: row R in plane -> byte R*64 + ((q ^ (R&3))*16); R&3==l15&3
  const int aoff = waveM * 8192 + l15 * 64 + ((q ^ (l15 & 3)) * 16);
  const int boff = waveN * 4096 + l15 * 64 + ((q ^ (l15 & 3)) * 16);
  const char* sA = smem;            // A planes: (buf*2+kk)<<14
  const char* sB = smem + 65536;    // B planes: 65536 + ((buf*2+kk)<<14)

  if (tid < 256) colAcc[tid] = 0.0f;

  f32x4 acc[8][4] = {};
  short8 a[4], b0[4], b1[4];

#define BARRIER() asm volatile("s_barrier" ::: "memory")
#define VMCNT4()  asm volatile("s_waitcnt vmcnt(4)" ::: "memory")
#define SP1() __builtin_amdgcn_s_setprio(1)
#define SP0() __builtin_amdgcn_s_setprio(0)

#define STAGE(T_, KK_, ISB_) do {                                             \
    const __hip_bfloat16* g0_ = (ISB_) ? gB0 : gA0;                           \
    const __hip_bfloat16* g1_ = (ISB_) ? gB1 : gA1;                           \
    const int ko_ = ((T_) & 7) * BK + (KK_) * 32;                             \
    const int pl_ = ((((T_) & 1) * 2 + (KK_)) << 14) + ((ISB_) ? 65536 : 0);  \
    gld_lds16(g0_ + ko_, ldsW0 + pl_);                                        \
    gld_lds16(g1_ + ko_, ldsW1 + pl_);                                        \
  } while (0)

#define LDA4(PK_, H_) do {                                                    \
    const char* p_ = sA + ((PK_) << 14) + aoff + (H_) * 4096;                 \
    a[0] = *(const short8*)(p_);                                              \
    a[1] = *(const short8*)(p_ + 1024);                                       \
    a[2] = *(const short8*)(p_ + 2048);                                       \
    a[3] = *(const short8*)(p_ + 3072);                                       \
  } while (0)

#define LDB4(PK_, BV_) do {                                                   \
    const char* p_ = sB + ((PK_) << 14) + boff;                               \
    BV_[0] = *(const short8*)(p_);                                            \
    BV_[1] = *(const short8*)(p_ + 1024);                                     \
    BV_[2] = *(const short8*)(p_ + 2048);                                     \
    BV_[3] = *(const short8*)(p_ + 3072);                                     \
  } while (0)

#define MFMA16(H_, BV_) do {                                                  \
    _Pragma("unroll")                                                         \
    for (int m_ = 0; m_ < 4; ++m_)                                            \
      _Pragma("unroll")                                                       \
      for (int n_ = 0; n_ < 4; ++n_)                                          \
        acc[(H_) * 4 + m_][n_] = __builtin_amdgcn_mfma_f32_16x16x32_bf16(     \
            a[m_], BV_[n_], acc[(H_) * 4 + m_][n_], 0, 0, 0);                 \
  } while (0)

  // plane index PK_: buf0kk0=0 buf0kk1=1 buf1kk0=2 buf1kk1=3
#define ITER(U_, V_) do {                                                     \
    /* ph0 */ LDA4(0, 0); LDB4(0, b0); STAGE((V_), 1, 0);                     \
    BARRIER(); SP1(); MFMA16(0, b0); SP0(); BARRIER();                        \
    /* ph1 */ LDA4(0, 1); STAGE((V_), 1, 1);                                  \
    BARRIER(); SP1(); MFMA16(1, b0); SP0(); BARRIER();                        \
    /* ph2 */ LDA4(1, 0); LDB4(1, b1); STAGE((U_) + 2, 0, 0);                 \
    BARRIER(); SP1(); MFMA16(0, b1); SP0(); BARRIER();                        \
    /* ph3 */ LDA4(1, 1); STAGE((U_) + 2, 0, 1); VMCNT4();                    \
    BARRIER(); SP1(); MFMA16(1, b1); SP0(); BARRIER();                        \
    /* ph4 */ LDA4(2, 0); LDB4(2, b0); STAGE((U_) + 2, 1, 0);                 \
    BARRIER(); SP1(); MFMA16(0, b0); SP0(); BARRIER();                        \
    /* ph5 */ LDA4(2, 1); STAGE((U_) + 2, 1, 1);                              \
    BARRIER(); SP1(); MFMA16(1, b0); SP0(); BARRIER();                        \
    /* ph6 */ LDA4(3, 0); LDB4(3, b1); STAGE((V_) + 2, 0, 0);                 \
    BARRIER(); SP1(); MFMA16(0, b1); SP0(); BARRIER();                        \
    /* ph7 */ LDA4(3, 1); STAGE((V_) + 2, 0, 1); VMCNT4();                    \
    BARRIER(); SP1(); MFMA16(1, b1); SP0(); BARRIER();                        \
  } while (0)

  // prologue: tile0 all 4 planes + tile1 kk0 planes; vmcnt(4) leaves tile1's
  // 4 loads in flight -> tile0 guaranteed; steady-state from iteration 0.
  STAGE(0, 0, 0); STAGE(0, 0, 1); STAGE(0, 1, 0); STAGE(0, 1, 1);
  STAGE(1, 0, 0); STAGE(1, 0, 1);
  asm volatile("s_waitcnt vmcnt(4) lgkmcnt(0)" ::: "memory");
  BARRIER();

  ITER(0, 1);
  ITER(2, 3);
  ITER(4, 5);
  ITER(6, 7);

  // drain wrap-prefetches before reusing staging LDS as reduction buffer
  asm volatile("s_waitcnt vmcnt(0)" ::: "memory");
  BARRIER();

  // --- epilogue: exp2 (log2-domain acc), row/col partial sums ---
  float* redBuf = (float*)smem;     // [64 (waveN,l15) slots][260 pitch] fp32
  float cp[4] = {0.f, 0.f, 0.f, 0.f};
  f32x4 rp[8];

#pragma unroll
  for (int mi = 0; mi < 8; ++mi) {
    f32x4 r = {0.f, 0.f, 0.f, 0.f};
#pragma unroll
    for (int ni = 0; ni < 4; ++ni) {
      const int lc = waveN * 64 + ni * 16 + l15;
#pragma unroll
      for (int rr = 0; rr < 4; ++rr) {
        const int lr = waveM * 128 + mi * 16 + q * 4 + rr;
        const float s = acc[mi][ni][rr];
        float e = exp2f(s);
        if (diagTile && lc == lr) e = 0.0f;   // exclude self-sim
        r[rr] += e;
        cp[ni] += e;
        if (hasPos && lc == lr) {
          const int gi = rowBase + lr;
          possim[gi] = s;
          possim[gi + BATCH / 2] = s;
        }
      }
    }
    rp[mi] = r;
  }

  {  // transpose-store per-lane row partials (16B aligned: pitch 260)
    float* wb = redBuf + (waveN * 16 + l15) * 260 + waveM * 128 + q * 4;
#pragma unroll
    for (int mi = 0; mi < 8; ++mi) *(f32x4*)(wb + mi * 16) = rp[mi];
  }

  if (!diagTile) {  // column credit (symmetry): reduce quads, LDS atomic
#pragma unroll
    for (int ni = 0; ni < 4; ++ni) {
      float c = cp[ni];
      c += __shfl_xor(c, 16, 64);
      c += __shfl_xor(c, 32, 64);
      if (q == 0) atomicAdd(&colAcc[waveN * 64 + ni * 16 + l15], c);
    }
  }
  asm volatile("s_waitcnt lgkmcnt(0)" ::: "memory");
  BARRIER();

  {  // 512 threads: each sums one (row, half of 64 partial slots)
    const int row = tid >> 1, half = tid & 1;
    const float* bp = redBuf + (half * 32) * 260 + row;
    float ssum = 0.f;
#pragma unroll
    for (int j = 0; j < 32; ++j) ssum += bp[j * 260];
    atomicAdd(&rowsum[rowBase + row], ssum);
  }
  if (!diagTile && tid < 256)
    atomicAdd(&rowsum[colBase + tid], colAcc[tid]);
}

// ---------------------------------------------------------------------------
// Kernel 3: loss = mean_i( log(rowsum_i) - possim_i * ln2 )
// ---------------------------------------------------------------------------
__global__ __launch_bounds__(1024) void finalize_kernel(
    const float* __restrict__ rowsum, const float* __restrict__ possim,
    float* __restrict__ out) {
  float acc = 0.0f;
  for (int i = threadIdx.x; i < BATCH; i += 1024)
    acc += __logf(rowsum[i]) - possim[i] * LN2;
#pragma unroll
  for (int m = 32; m > 0; m >>= 1) acc += __shfl_xor(acc, m, 64);
  __shared__ float ws[16];
  const int lane = threadIdx.x & 63, wv = threadIdx.x >> 6;
  if (lane == 0) ws[wv] = acc;
  __syncthreads();
  if (threadIdx.x == 0) {
    float tot = 0.0f;
#pragma unroll
    for (int k = 0; k < 16; ++k) tot += ws[k];
    out[0] = tot * (1.0f / (float)BATCH);
  }
}

extern "C" void kernel_launch(void* const* d_in, const int* in_sizes, int n_in,
                              void* d_out, int out_size, void* d_ws, size_t ws_size,
                              hipStream_t stream) {
  const float* x = (const float*)d_in[0];
  float* out = (float*)d_out;

  __hip_bfloat16* Fb = (__hip_bfloat16*)d_ws;
  float* rowsum = (float*)((char*)d_ws + (size_t)BATCH * DIM * sizeof(__hip_bfloat16));
  float* possim = rowsum + BATCH;

  static bool attr_done = false;
  if (!attr_done) {
    (void)hipFuncSetAttribute(reinterpret_cast<const void*>(sim_lse_kernel),
                              hipFuncAttributeMaxDynamicSharedMemorySize, 132096);
    attr_done = true;
  }

  normalize_bf16<<<BATCH / 4, 256, 0, stream>>>(x, Fb, rowsum);
  sim_lse_kernel<<<NPAIR, 512, 132096, stream>>>(Fb, rowsum, possim);
  finalize_kernel<<<1, 1024, 0, stream>>>(rowsum, possim, out);
}

// Round 2
// 128.383 us; speedup vs baseline: 1.0638x; 1.0638x over previous
//
#include <hip/hip_runtime.h>
#include <hip/hip_bf16.h>
#include <stdint.h>

#define BATCH 8192
#define DIM   512
#define BM    256                     // pair tile (similarity block is 256x256)
#define NT    (BATCH / BM)            // 32 tiles per dim
#define NPAIR (NT * (NT + 1) / 2)     // 528 upper-triangle tile pairs
#define NBLK  (NPAIR * 2)             // 1056 blocks: each does 128x256 of a pair

// Fb = F_norm * sqrt(log2(e)/T) so acc = Fb·Fbᵀ is already log2-domain logits.
#define FEAT_SCALE 4.5398164f         // sqrt(1.4426950409/0.07)
#define LN2        0.69314718055994531f

typedef __attribute__((ext_vector_type(8))) short short8;
typedef __attribute__((ext_vector_type(4))) float f32x4;

__device__ __forceinline__ void gld_lds16(const void* g, void* l) {
  __builtin_amdgcn_global_load_lds(
      (__attribute__((address_space(1))) void*)(uintptr_t)g,
      (__attribute__((address_space(3))) void*)(uintptr_t)l,
      16, 0, 0);
}

// ---------------------------------------------------------------------------
// Kernel 1: row-normalize fp32 -> bf16 * FEAT_SCALE. One wave per row.
// ---------------------------------------------------------------------------
__global__ __launch_bounds__(256) void normalize_bf16(
    const float* __restrict__ x, __hip_bfloat16* __restrict__ o,
    float* __restrict__ rowsum) {
  const int wv = threadIdx.x >> 6, lane = threadIdx.x & 63;
  const int row = blockIdx.x * 4 + wv;
  if (lane == 0) rowsum[row] = 0.0f;
  const float4* xr = (const float4*)(x + (size_t)row * DIM);
  const float4 v0 = xr[lane];
  const float4 v1 = xr[lane + 64];
  float ss = v0.x * v0.x + v0.y * v0.y + v0.z * v0.z + v0.w * v0.w +
             v1.x * v1.x + v1.y * v1.y + v1.z * v1.z + v1.w * v1.w;
#pragma unroll
  for (int m = 32; m > 0; m >>= 1) ss += __shfl_xor(ss, m, 64);
  const float inv = FEAT_SCALE / fmaxf(sqrtf(ss), 1e-12f);
  ushort4 p0, p1;
  p0.x = __bfloat16_as_ushort(__float2bfloat16(v0.x * inv));
  p0.y = __bfloat16_as_ushort(__float2bfloat16(v0.y * inv));
  p0.z = __bfloat16_as_ushort(__float2bfloat16(v0.z * inv));
  p0.w = __bfloat16_as_ushort(__float2bfloat16(v0.w * inv));
  p1.x = __bfloat16_as_ushort(__float2bfloat16(v1.x * inv));
  p1.y = __bfloat16_as_ushort(__float2bfloat16(v1.y * inv));
  p1.z = __bfloat16_as_ushort(__float2bfloat16(v1.z * inv));
  p1.w = __bfloat16_as_ushort(__float2bfloat16(v1.w * inv));
  ushort4* orow = (ushort4*)(o + (size_t)row * DIM);
  orow[lane]      = p0;
  orow[lane + 64] = p1;
}

// ---------------------------------------------------------------------------
// Kernel 2: 1056 blocks, each computes a 128x256 slice (half of an upper-
// triangle 256x256 tile-pair, split along M so the grid quantizes well onto
// 256 CUs). 8 waves as 2M(64r) x 4N(64c), acc[4][4] per wave.
//
// Pipeline: BK=64 split into kk-planes of 32: A-plane [128][32] = 8 KB
// (1 global_load_lds call), B-plane [256][32] = 16 KB (2 calls). Double-
// buffered: LDS 96 KB + 1 KB colAcc -> 1 block/CU, 2 waves/SIMD.
// Uniform phase (16 total): {4 ds_read A, 4 ds_read B, stage 3 calls,
// vmcnt(6), s_barrier, setprio(1), 16 MFMA, setprio(0), s_barrier}.
// Stage rule: phase(T,kk0) stages (T+1,kk1); phase(T,kk1) stages (T+2,kk0).
// Induction: after phase p's vmcnt(6) everything through set S_{p-1} is
// complete; phase p reads S_{p-3} -> resident >=2 phases + 1 barrier early.
// Last-tile stages wrap to tiles 0/1 (harmless rewrite) keeping counts
// uniform; one vmcnt(0) before epilogue reuses staging LDS.
//
// Swizzle (fixes round-1's 4-way conflict): 16B slot s ^= (row>>1)&3 on BOTH
// the staging global source and the ds_read offset. Bank group of a read =
// (row&1, q^((row>>1)&3)) -> 8 groups x 2 lanes = 2-way = free (m136).
// ---------------------------------------------------------------------------
__global__ __launch_bounds__(512, 2) void sim_lse_kernel(
    const __hip_bfloat16* __restrict__ F, float* __restrict__ rowsum,
    float* __restrict__ possim) {
  extern __shared__ char smem[];
  float* colAcc = (float*)(smem + 98304);

  const int t  = blockIdx.x;
  const int pr = t >> 1;          // pair index 0..527
  const int hb = t & 1;           // which 128-row half of the pair
  int by = (int)((65.0f - sqrtf(65.0f * 65.0f - 8.0f * (float)pr)) * 0.5f);
  if (by > NT - 1) by = NT - 1;
  if (by < 0) by = 0;
  while ((by + 1) * (65 - (by + 1)) / 2 <= pr) ++by;
  while (by * (65 - by) / 2 > pr) --by;
  const int bx = by + (pr - by * (65 - by) / 2);
  const bool diagTile = (bx == by);
  const bool hasPos = (bx == by + NT / 2);

  const int rowB = by * BM + hb * 128;   // 128 rows
  const int colB = bx * BM;              // 256 cols

  const int tid  = threadIdx.x;
  const int lane = tid & 63;
  const int wv   = tid >> 6;
  const int q    = lane >> 4;
  const int l15  = lane & 15;
  const int waveM = wv >> 2;   // 0..1 -> 64-row half
  const int waveN = wv & 3;    // 0..3 -> 64-col quarter

  // staging sources: thread covers (row r, 16B slot s), source slot pre-
  // swizzled s ^ ((r>>1)&3) so the linear LDS write + swizzled read match.
  const int rs = tid >> 2, ss = tid & 3;
  const int sw = ss ^ ((rs >> 1) & 3);
  const __hip_bfloat16* gA  = F + (size_t)(rowB + rs) * DIM + sw * 8;
  const __hip_bfloat16* gB0 = F + (size_t)(colB + rs) * DIM + sw * 8;
  const __hip_bfloat16* gB1 = gB0 + (size_t)128 * DIM;   // (128+r)>>1&3 == r>>1&3

  // ds_read offsets (swizzled slot): row stride 64 B within a plane.
  const int swz  = (q ^ ((l15 >> 1) & 3)) * 16;
  const int aoff = (waveM * 64 + l15) * 64 + swz;        // in 8 KB A plane
  const int boff = (waveN * 64 + l15) * 64 + swz;        // in 16 KB B plane

  if (tid < 256) colAcc[tid] = 0.0f;

  f32x4 acc[4][4] = {};
  short8 a[4], b[4];

  // plane bases: A(buf,kk) at (buf*2+kk)*8192; B(buf,kk) at 32768+(buf*2+kk)*16384
#define STAGE(T_, KK_) do {                                                   \
    const int ko_ = ((T_) & 7) * 64 + (KK_) * 32;                             \
    const int pb_ = ((T_) & 1) * 2 + (KK_);                                   \
    gld_lds16(gA  + ko_, smem + pb_ * 8192 + wv * 1024);                      \
    gld_lds16(gB0 + ko_, smem + 32768 + pb_ * 16384 + wv * 1024);             \
    gld_lds16(gB1 + ko_, smem + 32768 + pb_ * 16384 + 8192 + wv * 1024);      \
  } while (0)

#define PHASE(TB_, KK_, ST_, SKK_) do {                                       \
    const char* pa_ = smem + ((TB_) * 2 + (KK_)) * 8192 + aoff;               \
    a[0] = *(const short8*)(pa_);                                             \
    a[1] = *(const short8*)(pa_ + 1024);                                      \
    a[2] = *(const short8*)(pa_ + 2048);                                      \
    a[3] = *(const short8*)(pa_ + 3072);                                      \
    const char* pb_ = smem + 32768 + ((TB_) * 2 + (KK_)) * 16384 + boff;      \
    b[0] = *(const short8*)(pb_);                                             \
    b[1] = *(const short8*)(pb_ + 1024);                                      \
    b[2] = *(const short8*)(pb_ + 2048);                                      \
    b[3] = *(const short8*)(pb_ + 3072);                                      \
    STAGE(ST_, SKK_);                                                         \
    asm volatile("s_waitcnt vmcnt(6)" ::: "memory");                          \
    __builtin_amdgcn_s_barrier();                                             \
    __builtin_amdgcn_s_setprio(1);                                            \
    _Pragma("unroll")                                                         \
    for (int m_ = 0; m_ < 4; ++m_)                                            \
      _Pragma("unroll")                                                       \
      for (int n_ = 0; n_ < 4; ++n_)                                          \
        acc[m_][n_] = __builtin_amdgcn_mfma_f32_16x16x32_bf16(                \
            a[m_], b[n_], acc[m_][n_], 0, 0, 0);                              \
    __builtin_amdgcn_s_setprio(0);                                            \
    __builtin_amdgcn_s_barrier();                                             \
  } while (0)

  // prologue: tile0 both kk planes + tile1 kk0 (9 calls); vmcnt(3) -> tile0
  // resident, tile1.kk0's 3 calls in flight (completed by phase1's vmcnt(6),
  // one phase + barrier before its phase-2 read).
  STAGE(0, 0); STAGE(0, 1); STAGE(1, 0);
  asm volatile("s_waitcnt vmcnt(3)" ::: "memory");
  __builtin_amdgcn_s_barrier();

#pragma unroll
  for (int T = 0; T < 8; ++T) {
    PHASE(T & 1, 0, T + 1, 1);
    PHASE(T & 1, 1, T + 2, 0);
  }

  // drain wrap-prefetches before reusing staging LDS as reduction buffer
  asm volatile("s_waitcnt vmcnt(0)" ::: "memory");
  __builtin_amdgcn_s_barrier();

  // --- epilogue: exp2 (log2-domain acc), row/col partial sums ---
  float* redBuf = (float*)smem;   // [64 slots (waveN,l15)][pitch 132] fp32
  float cp[4] = {0.f, 0.f, 0.f, 0.f};
  f32x4 rp[4];

#pragma unroll
  for (int mi = 0; mi < 4; ++mi) {
    f32x4 r = {0.f, 0.f, 0.f, 0.f};
#pragma unroll
    for (int ni = 0; ni < 4; ++ni) {
      const int lc = waveN * 64 + ni * 16 + l15;         // 0..255
#pragma unroll
      for (int rr = 0; rr < 4; ++rr) {
        const int lr = waveM * 64 + mi * 16 + q * 4 + rr;  // 0..127
        const float s = acc[mi][ni][rr];
        float e = exp2f(s);
        if (diagTile && lc == hb * 128 + lr) e = 0.0f;   // exclude self-sim
        r[rr] += e;
        cp[ni] += e;
        if (hasPos && lc == hb * 128 + lr) {
          const int gi = rowB + lr;
          possim[gi] = s;
          possim[gi + BATCH / 2] = s;
        }
      }
    }
    rp[mi] = r;
  }

  {  // transpose-store per-lane row partials; pitch 132 dw keeps 16B align
    float* wb = redBuf + (waveN * 16 + l15) * 132 + waveM * 64 + q * 4;
#pragma unroll
    for (int mi = 0; mi < 4; ++mi) *(f32x4*)(wb + mi * 16) = rp[mi];
  }

  if (!diagTile) {  // column credit (symmetry): reduce quads, LDS atomic
#pragma unroll
    for (int ni = 0; ni < 4; ++ni) {
      float c = cp[ni];
      c += __shfl_xor(c, 16, 64);
      c += __shfl_xor(c, 32, 64);
      if (q == 0) atomicAdd(&colAcc[waveN * 64 + ni * 16 + l15], c);
    }
  }
  asm volatile("s_waitcnt lgkmcnt(0)" ::: "memory");
  __builtin_amdgcn_s_barrier();

  {  // 512 threads: 4 threads per row, each sums 16 of 64 partial slots
    const int row = tid >> 2, g = tid & 3;
    const float* bp = redBuf + g * 132 + row;
    float s = 0.f;
#pragma unroll
    for (int j = 0; j < 16; ++j) s += bp[j * 528];   // slot stride 4*132
    s += __shfl_xor(s, 1, 64);
    s += __shfl_xor(s, 2, 64);
    if (g == 0) atomicAdd(&rowsum[rowB + row], s);
  }
  if (!diagTile && tid < 256)
    atomicAdd(&rowsum[colB + tid], colAcc[tid]);
}

// ---------------------------------------------------------------------------
// Kernel 3: loss = mean_i( log(rowsum_i) - possim_i * ln2 )
// ---------------------------------------------------------------------------
__global__ __launch_bounds__(1024) void finalize_kernel(
    const float* __restrict__ rowsum, const float* __restrict__ possim,
    float* __restrict__ out) {
  float acc = 0.0f;
  for (int i = threadIdx.x; i < BATCH; i += 1024)
    acc += __logf(rowsum[i]) - possim[i] * LN2;
#pragma unroll
  for (int m = 32; m > 0; m >>= 1) acc += __shfl_xor(acc, m, 64);
  __shared__ float ws[16];
  const int lane = threadIdx.x & 63, wv = threadIdx.x >> 6;
  if (lane == 0) ws[wv] = acc;
  __syncthreads();
  if (threadIdx.x == 0) {
    float tot = 0.0f;
#pragma unroll
    for (int k = 0; k < 16; ++k) tot += ws[k];
    out[0] = tot * (1.0f / (float)BATCH);
  }
}

extern "C" void kernel_launch(void* const* d_in, const int* in_sizes, int n_in,
                              void* d_out, int out_size, void* d_ws, size_t ws_size,
                              hipStream_t stream) {
  const float* x = (const float*)d_in[0];
  float* out = (float*)d_out;

  __hip_bfloat16* Fb = (__hip_bfloat16*)d_ws;
  float* rowsum = (float*)((char*)d_ws + (size_t)BATCH * DIM * sizeof(__hip_bfloat16));
  float* possim = rowsum + BATCH;

  static bool attr_done = false;
  if (!attr_done) {
    (void)hipFuncSetAttribute(reinterpret_cast<const void*>(sim_lse_kernel),
                              hipFuncAttributeMaxDynamicSharedMemorySize, 99328);
    attr_done = true;
  }

  normalize_bf16<<<BATCH / 4, 256, 0, stream>>>(x, Fb, rowsum);
  sim_lse_kernel<<<NBLK, 512, 99328, stream>>>(Fb, rowsum, possim);
  finalize_kernel<<<1, 1024, 0, stream>>>(rowsum, possim, out);
}

// Round 3
// 120.535 us; speedup vs baseline: 1.1330x; 1.0651x over previous
//
#include <hip/hip_runtime.h>
#include <hip/hip_bf16.h>
#include <stdint.h>

#define BATCH 8192
#define DIM   512
#define BM    256                     // pair tile: 256x256 of the sim matrix
#define NT    (BATCH / BM)            // 32 tiles per dim
#define NPAIR (NT * (NT + 1) / 2)     // 528 upper-triangle tile pairs

// Fb = F_norm * sqrt(log2(e)/T) so acc = Fb·Fbᵀ is already log2-domain logits.
#define FEAT_SCALE 4.5398164f         // sqrt(1.4426950409/0.07)
#define LN2        0.69314718055994531f

typedef __attribute__((ext_vector_type(8))) short short8;
typedef __attribute__((ext_vector_type(4))) float f32x4;

__device__ __forceinline__ void gld_lds16(const void* g, void* l) {
  __builtin_amdgcn_global_load_lds(
      (__attribute__((address_space(1))) void*)(uintptr_t)g,
      (__attribute__((address_space(3))) void*)(uintptr_t)l,
      16, 0, 0);
}

// ---------------------------------------------------------------------------
// Kernel 1: row-normalize fp32 -> bf16 * FEAT_SCALE. One wave per row.
// ---------------------------------------------------------------------------
__global__ __launch_bounds__(256) void normalize_bf16(
    const float* __restrict__ x, __hip_bfloat16* __restrict__ o,
    float* __restrict__ rowsum) {
  const int wv = threadIdx.x >> 6, lane = threadIdx.x & 63;
  const int row = blockIdx.x * 4 + wv;
  if (lane == 0) rowsum[row] = 0.0f;
  const float4* xr = (const float4*)(x + (size_t)row * DIM);
  const float4 v0 = xr[lane];
  const float4 v1 = xr[lane + 64];
  float ss = v0.x * v0.x + v0.y * v0.y + v0.z * v0.z + v0.w * v0.w +
             v1.x * v1.x + v1.y * v1.y + v1.z * v1.z + v1.w * v1.w;
#pragma unroll
  for (int m = 32; m > 0; m >>= 1) ss += __shfl_xor(ss, m, 64);
  const float inv = FEAT_SCALE / fmaxf(sqrtf(ss), 1e-12f);
  ushort4 p0, p1;
  p0.x = __bfloat16_as_ushort(__float2bfloat16(v0.x * inv));
  p0.y = __bfloat16_as_ushort(__float2bfloat16(v0.y * inv));
  p0.z = __bfloat16_as_ushort(__float2bfloat16(v0.z * inv));
  p0.w = __bfloat16_as_ushort(__float2bfloat16(v0.w * inv));
  p1.x = __bfloat16_as_ushort(__float2bfloat16(v1.x * inv));
  p1.y = __bfloat16_as_ushort(__float2bfloat16(v1.y * inv));
  p1.z = __bfloat16_as_ushort(__float2bfloat16(v1.z * inv));
  p1.w = __bfloat16_as_ushort(__float2bfloat16(v1.w * inv));
  ushort4* orow = (ushort4*)(o + (size_t)row * DIM);
  orow[lane]      = p0;
  orow[lane + 64] = p1;
}

// ---------------------------------------------------------------------------
// Kernel 2: 528 blocks, one full 256x256 upper-triangle tile-pair each.
// 8 waves as 2M x 4N, per-wave output 128x64 (acc[8][4]) -> 375 B LDS read
// per MFMA (m201 geometry); LDS-read pipe (1536 cy/K-tile) < MFMA (2483 cy).
//
// LDS: 2 buffers x {A,B} x 2 halves of [128 rows][64 k] bf16 (16 KB planes)
// = 128 KiB, + 1 KB colAcc. K-tile BK=64; 8 K-tiles for DIM=512.
// Swizzle: 16B-chunk ^= (row&7) on BOTH gld source and ds_read (involution).
//
// Sync structure: ONE barrier per K-tile (buffer swap point). Within a tile,
// 4 phases {ds_read frags | stage T+1 half | 16 MFMA} run wave-async (no
// barriers) -> one wave's MFMA overlaps another's LDS drain. Phase order is
// pinned with sched_barrier(0) to bound live registers. Stages for T+1 are
// issued at phases 0/1 and drained by vmcnt(0) >=2 phases later (free).
// ---------------------------------------------------------------------------
__global__ __launch_bounds__(512, 2) void sim_lse_kernel(
    const __hip_bfloat16* __restrict__ F, float* __restrict__ rowsum,
    float* __restrict__ possim) {
  extern __shared__ char smem[];
  float* colAcc = (float*)(smem + 131072);

  const int pr = blockIdx.x;
  int by = (int)((65.0f - sqrtf(65.0f * 65.0f - 8.0f * (float)pr)) * 0.5f);
  if (by > NT - 1) by = NT - 1;
  if (by < 0) by = 0;
  while ((by + 1) * (65 - (by + 1)) / 2 <= pr) ++by;
  while (by * (65 - by) / 2 > pr) --by;
  const int bx = by + (pr - by * (65 - by) / 2);
  const bool diagTile = (bx == by);
  const bool hasPos = (bx == by + NT / 2);

  const int rowB = by * BM;
  const int colB = bx * BM;

  const int tid  = threadIdx.x;
  const int lane = tid & 63;
  const int wv   = tid >> 6;
  const int q    = lane >> 4;
  const int l15  = lane & 15;
  const int waveM = wv >> 2;   // 0..1 -> 128-row half of C
  const int waveN = wv & 3;    // 0..3 -> 64-col quarter of C

  // ---- staging source addressing (pre-swizzled chunk: c ^ (row&7)) ----
  const int r0 = tid >> 3, c0 = tid & 7;
  const int csrc = c0 ^ (r0 & 7);
  const __hip_bfloat16* gAp = F + (size_t)(rowB + r0) * DIM + csrc * 8;
  const __hip_bfloat16* gBp = F + (size_t)(colB + r0) * DIM + csrc * 8;

  // plane(buf, isB, h) = buf*65536 + isB*32768 + h*16384 (bytes)
#define STAGE_A(Tn) do {                                                      \
    const int kk_ = ((Tn) & 7) * 64;                                          \
    char* d_ = smem + ((Tn) & 1) * 65536 + wv * 1024;                         \
    gld_lds16(gAp + kk_,                 d_);                                 \
    gld_lds16(gAp + kk_ + 32768,         d_ + 8192);                          \
    gld_lds16(gAp + kk_ + 65536,         d_ + 16384);                         \
    gld_lds16(gAp + kk_ + 98304,         d_ + 24576);                         \
  } while (0)
#define STAGE_B(Tn) do {                                                      \
    const int kk_ = ((Tn) & 7) * 64;                                          \
    char* d_ = smem + ((Tn) & 1) * 65536 + 32768 + wv * 1024;                 \
    gld_lds16(gBp + kk_,                 d_);                                 \
    gld_lds16(gBp + kk_ + 32768,         d_ + 8192);                          \
    gld_lds16(gBp + kk_ + 65536,         d_ + 16384);                         \
    gld_lds16(gBp + kk_ + 98304,         d_ + 24576);                         \
  } while (0)

  // ---- fragment read addressing (swizzled chunk) ----
  const int cs0 = ((q)     ^ (l15 & 7)) * 16;   // k-slice 0 (k 0..31)
  const int cs1 = ((4 + q) ^ (l15 & 7)) * 16;   // k-slice 1 (k 32..63)
  const int abase = waveM * 16384 + l15 * 128;
  const int bbase = 32768 + (waveN >> 1) * 16384 + ((waveN & 1) * 64 + l15) * 128;

  short8 a[4], b[4];
  f32x4 acc[8][4] = {};

#define RD_B(BF_, CS_) do {                                                   \
    const char* p_ = smem + (BF_) * 65536 + bbase + (CS_);                    \
    b[0] = *(const short8*)(p_);                                              \
    b[1] = *(const short8*)(p_ + 2048);                                       \
    b[2] = *(const short8*)(p_ + 4096);                                       \
    b[3] = *(const short8*)(p_ + 6144);                                       \
  } while (0)
#define RD_A(BF_, LH_, CS_) do {                                              \
    const char* p_ = smem + (BF_) * 65536 + abase + (LH_) * 8192 + (CS_);     \
    a[0] = *(const short8*)(p_);                                              \
    a[1] = *(const short8*)(p_ + 2048);                                       \
    a[2] = *(const short8*)(p_ + 4096);                                       \
    a[3] = *(const short8*)(p_ + 6144);                                       \
  } while (0)
#define MFMA16(LH_) do {                                                      \
    __builtin_amdgcn_s_setprio(1);                                            \
    _Pragma("unroll")                                                         \
    for (int m_ = 0; m_ < 4; ++m_)                                            \
      _Pragma("unroll")                                                       \
      for (int n_ = 0; n_ < 4; ++n_)                                          \
        acc[(LH_) * 4 + m_][n_] = __builtin_amdgcn_mfma_f32_16x16x32_bf16(    \
            a[m_], b[n_], acc[(LH_) * 4 + m_][n_], 0, 0, 0);                  \
    __builtin_amdgcn_s_setprio(0);                                            \
    __builtin_amdgcn_sched_barrier(0);                                        \
  } while (0)

  if (tid < 256) colAcc[tid] = 0.0f;

  // prologue: stage tile 0, drain, barrier
  STAGE_A(0); STAGE_B(0);
  asm volatile("s_waitcnt vmcnt(0)" ::: "memory");
  __builtin_amdgcn_s_barrier();

#pragma unroll
  for (int T = 0; T < 8; ++T) {
    const int bf = T & 1;
    // phase 0: B(s0) + A-lo(s0) reads | stage T+1 A | MFMA lo
    RD_B(bf, cs0); RD_A(bf, 0, cs0);
    if (T < 7) STAGE_A(T + 1);
    MFMA16(0);
    // phase 1: A-hi(s0) | stage T+1 B | MFMA hi
    RD_A(bf, 1, cs0);
    if (T < 7) STAGE_B(T + 1);
    MFMA16(1);
    // phase 2: B(s1) + A-lo(s1) | MFMA lo
    RD_B(bf, cs1); RD_A(bf, 0, cs1);
    MFMA16(0);
    // phase 3: A-hi(s1) | MFMA hi
    RD_A(bf, 1, cs1);
    MFMA16(1);
    // tile boundary: T+1's stages (issued >=2 phases ago) drained; swap
    asm volatile("s_waitcnt vmcnt(0)" ::: "memory");
    __builtin_amdgcn_s_barrier();
  }

  // --- epilogue: exp2 (log2-domain acc), row/col partial sums ---
  float* redBuf = (float*)smem;   // [64 slots (waveN,l15)][pitch 260] fp32
  float cp[4] = {0.f, 0.f, 0.f, 0.f};
  f32x4 rp[8];

#pragma unroll
  for (int mi = 0; mi < 8; ++mi) {
    f32x4 r = {0.f, 0.f, 0.f, 0.f};
#pragma unroll
    for (int ni = 0; ni < 4; ++ni) {
      const int lc = waveN * 64 + ni * 16 + l15;            // 0..255
#pragma unroll
      for (int rr = 0; rr < 4; ++rr) {
        const int lr = waveM * 128 + mi * 16 + q * 4 + rr;  // 0..255
        const float s = acc[mi][ni][rr];
        float e = exp2f(s);
        if (diagTile && lc == lr) e = 0.0f;                 // exclude self
        r[rr] += e;
        cp[ni] += e;
        if (hasPos && lc == lr) {
          possim[rowB + lr] = s;
          possim[rowB + lr + BATCH / 2] = s;
        }
      }
    }
    rp[mi] = r;
  }

  {  // transpose-store per-lane row partials (pitch 260 dw = 1040 B, 16B ok)
    float* wb = redBuf + (waveN * 16 + l15) * 260 + waveM * 128 + q * 4;
#pragma unroll
    for (int mi = 0; mi < 8; ++mi) *(f32x4*)(wb + mi * 16) = rp[mi];
  }

  if (!diagTile) {  // column credit (symmetry): reduce quads, LDS atomic
#pragma unroll
    for (int ni = 0; ni < 4; ++ni) {
      float c = cp[ni];
      c += __shfl_xor(c, 16, 64);
      c += __shfl_xor(c, 32, 64);
      if (q == 0) atomicAdd(&colAcc[waveN * 64 + ni * 16 + l15], c);
    }
  }
  asm volatile("s_waitcnt lgkmcnt(0)" ::: "memory");
  __builtin_amdgcn_s_barrier();

  {  // 512 threads: 2 threads per row, each sums 32 of 64 partial slots
    const int row = tid >> 1, half = tid & 1;
    const float* bp = redBuf + half * 32 * 260 + row;
    float ssum = 0.f;
#pragma unroll
    for (int j = 0; j < 32; ++j) ssum += bp[j * 260];
    ssum += __shfl_xor(ssum, 1, 64);
    if (half == 0) atomicAdd(&rowsum[rowB + row], ssum);
  }
  if (!diagTile && tid < 256)
    atomicAdd(&rowsum[colB + tid], colAcc[tid]);
}

// ---------------------------------------------------------------------------
// Kernel 3: loss = mean_i( log(rowsum_i) - possim_i * ln2 )
// ---------------------------------------------------------------------------
__global__ __launch_bounds__(1024) void finalize_kernel(
    const float* __restrict__ rowsum, const float* __restrict__ possim,
    float* __restrict__ out) {
  float acc = 0.0f;
  for (int i = threadIdx.x; i < BATCH; i += 1024)
    acc += __logf(rowsum[i]) - possim[i] * LN2;
#pragma unroll
  for (int m = 32; m > 0; m >>= 1) acc += __shfl_xor(acc, m, 64);
  __shared__ float ws[16];
  const int lane = threadIdx.x & 63, wv = threadIdx.x >> 6;
  if (lane == 0) ws[wv] = acc;
  __syncthreads();
  if (threadIdx.x == 0) {
    float tot = 0.0f;
#pragma unroll
    for (int k = 0; k < 16; ++k) tot += ws[k];
    out[0] = tot * (1.0f / (float)BATCH);
  }
}

extern "C" void kernel_launch(void* const* d_in, const int* in_sizes, int n_in,
                              void* d_out, int out_size, void* d_ws, size_t ws_size,
                              hipStream_t stream) {
  const float* x = (const float*)d_in[0];
  float* out = (float*)d_out;

  __hip_bfloat16* Fb = (__hip_bfloat16*)d_ws;
  float* rowsum = (float*)((char*)d_ws + (size_t)BATCH * DIM * sizeof(__hip_bfloat16));
  float* possim = rowsum + BATCH;

  static bool attr_done = false;
  if (!attr_done) {
    (void)hipFuncSetAttribute(reinterpret_cast<const void*>(sim_lse_kernel),
                              hipFuncAttributeMaxDynamicSharedMemorySize, 132096);
    attr_done = true;
  }

  normalize_bf16<<<BATCH / 4, 256, 0, stream>>>(x, Fb, rowsum);
  sim_lse_kernel<<<NPAIR, 512, 132096, stream>>>(Fb, rowsum, possim);
  finalize_kernel<<<1, 1024, 0, stream>>>(rowsum, possim, out);
}